// Round 7
// baseline (470.556 us; speedup 1.0000x reference)
//
#include <hip/hip_runtime.h>
#include <hip/hip_bf16.h>

#define NN   20000
#define NE   320000
#define KSEL 4096

typedef short bf16x8 __attribute__((ext_vector_type(8)));
typedef float f32x4  __attribute__((ext_vector_type(4)));

static __device__ __forceinline__ float bf2f(unsigned short u){
  return __uint_as_float(((unsigned int)u) << 16);
}
static __device__ __forceinline__ unsigned short f2bf(float f){
  unsigned int x = __float_as_uint(f);
  x += 0x7fffu + ((x >> 16) & 1u);   // round-to-nearest-even
  return (unsigned short)(x >> 16);
}
// async global->LDS, 16B/lane; LDS dest = wave-uniform base + lane*16
static __device__ __forceinline__ void gld_lds16(const unsigned short* g, unsigned short* l){
  __builtin_amdgcn_global_load_lds(
      (const __attribute__((address_space(1))) unsigned int*)g,
      (__attribute__((address_space(3))) unsigned int*)l, 16, 0, 0);
}

// ---------------- prep0: [0,48) W 64x64 tile-transpose ; [48,68) zero counts + label partials
__global__ __launch_bounds__(256) void k_prep0(const float* __restrict__ W1,
    const float* __restrict__ Wsd, const float* __restrict__ W2,
    const int* __restrict__ labels,
    unsigned short* __restrict__ Wt, int* __restrict__ counts, int* __restrict__ partA){
  int b = blockIdx.x, tid = threadIdx.x;
  if (b < 48){
    __shared__ unsigned short lt[64 * 65];
    int w = b >> 4, t = b & 15;
    int tR = (t >> 2) * 64, tC = (t & 3) * 64;    // k-block, o-block
    const float* W = (w == 0) ? W1 : (w == 1 ? Wsd : W2);
    #pragma unroll
    for (int it = 0; it < 16; ++it){
      int lin = it * 256 + tid;
      int r = lin >> 6, c = lin & 63;             // k-off, o-off (coalesced read)
      lt[c * 65 + r] = f2bf(W[(size_t)(tR + r) * 256 + tC + c]);
    }
    __syncthreads();
    #pragma unroll
    for (int it = 0; it < 16; ++it){
      int lin = it * 256 + tid;
      int o = lin >> 6, k = lin & 63;             // coalesced write
      Wt[(size_t)w * 65536 + (size_t)(tC + o) * 256 + tR + k] = lt[o * 65 + k];
    }
  } else {
    __shared__ int ws[4];
    int z = b - 48, lane = tid & 63, wv = tid >> 6;
    if (tid < 250) *(int4*)&counts[z * 1000 + tid * 4] = make_int4(0, 0, 0, 0);
    int base = z * 1024 + tid * 4;
    int s = 0;
    #pragma unroll
    for (int j = 0; j < 4; ++j){
      int n0 = base + j;
      if (n0 < NN) s += (labels[n0] == 1) ? 1 : 0;
    }
    #pragma unroll
    for (int off = 32; off; off >>= 1) s += __shfl_down(s, off, 64);
    if (lane == 0) ws[wv] = s;
    __syncthreads();
    if (tid == 0) partA[z] = ws[0] + ws[1] + ws[2] + ws[3];
  }
}

// ---------------- main1: [0,2500) X->bf16 (REP x8) ; [2500,3750) histogram (x1) ;
//                  [3750,3770) idx emit (REP x8). MEASUREMENT PROBE — remove reps next round.
__global__ __launch_bounds__(256) void k_main1(const float* __restrict__ X,
    const int* __restrict__ row, const int* __restrict__ labels,
    const int* __restrict__ partA,
    unsigned short* __restrict__ Xb, int* __restrict__ counts, int* __restrict__ idx){
  int b = blockIdx.x, tid = threadIdx.x;
  if (b < 2500){
    for (int rep = 0; rep < 8; ++rep){
      asm volatile("" ::: "memory");
      int i = (b * 256 + tid) * 8;
      float4 v0 = *(const float4*)(X + i);
      float4 v1 = *(const float4*)(X + i + 4);
      bf16x8 o;
      o[0] = (short)f2bf(v0.x); o[1] = (short)f2bf(v0.y);
      o[2] = (short)f2bf(v0.z); o[3] = (short)f2bf(v0.w);
      o[4] = (short)f2bf(v1.x); o[5] = (short)f2bf(v1.y);
      o[6] = (short)f2bf(v1.z); o[7] = (short)f2bf(v1.w);
      *(bf16x8*)(Xb + i) = o;
    }
  } else if (b < 3750){
    int e = (b - 2500) * 256 + tid;
    atomicAdd(&counts[row[e]], 1);
  } else {
    __shared__ int ws[4];
    __shared__ int boff_s;
    int bx = b - 3750;
    int lane = tid & 63, wv = tid >> 6;
    for (int rep = 0; rep < 8; ++rep){
      __syncthreads();                  // protect shared reuse across reps
      asm volatile("" ::: "memory");
      if (tid < 64){
        int v = (lane < 20) ? partA[lane] : 0;
        int acc = v;
        #pragma unroll
        for (int off = 1; off < 32; off <<= 1){
          int t = __shfl_up(acc, off, 64);
          if (lane >= off) acc += t;
        }
        if (lane == bx) boff_s = acc - v;   // exclusive prefix
      }
      int base = bx * 1024 + tid * 4;
      int c[4]; int s = 0;
      #pragma unroll
      for (int j = 0; j < 4; ++j){
        int n0 = base + j;
        c[j] = (n0 < NN && labels[n0] == 1) ? 1 : 0;
        s += c[j];
      }
      int incl = s;
      #pragma unroll
      for (int off = 1; off < 64; off <<= 1){
        int t = __shfl_up(incl, off, 64);
        if (lane >= off) incl += t;
      }
      if (lane == 63) ws[wv] = incl;
      __syncthreads();
      int woff = boff_s;
      for (int w = 0; w < wv; ++w) woff += ws[w];
      int off = woff + incl - s;
      #pragma unroll
      for (int j = 0; j < 4; ++j){
        if (c[j]){ if (off < KSEL) idx[off] = base + j; ++off; }
      }
    }
  }
}

// 20 blocks; each sums counts[0..base) itself, then scans its 1024-window -> start/cursor
__global__ __launch_bounds__(256) void k_row_emit(const int* __restrict__ counts,
    int* __restrict__ start, int* __restrict__ cursor){
  __shared__ int ws[4];
  __shared__ int red[4];
  int tid = threadIdx.x, lane = tid & 63, wv = tid >> 6;
  int base = blockIdx.x * 1024;
  int ps = 0;
  for (int i = tid * 4; i < base; i += 1024){
    int4 v = *(const int4*)&counts[i];
    ps += v.x + v.y + v.z + v.w;
  }
  #pragma unroll
  for (int off = 32; off; off >>= 1) ps += __shfl_down(ps, off, 64);
  if (lane == 0) red[wv] = ps;
  __syncthreads();
  int bpref = red[0] + red[1] + red[2] + red[3];
  int nb = base + tid * 4;
  int c[4]; int s = 0;
  #pragma unroll
  for (int j = 0; j < 4; ++j){
    int n0 = nb + j;
    c[j] = (n0 < NN) ? counts[n0] : 0;
    s += c[j];
  }
  int incl = s;
  #pragma unroll
  for (int off = 1; off < 64; off <<= 1){
    int t = __shfl_up(incl, off, 64);
    if (lane >= off) incl += t;
  }
  if (lane == 63) ws[wv] = incl;
  __syncthreads();
  int woff = bpref;
  for (int w = 0; w < wv; ++w) woff += ws[w];
  int run = woff + incl - s;
  #pragma unroll
  for (int j = 0; j < 4; ++j){
    int n0 = nb + j;
    if (n0 < NN){ start[n0] = run; cursor[n0] = run; run += c[j]; }
  }
  if (blockIdx.x == 0 && tid == 0) start[NN] = NE;
}

__global__ void k_scatter(const int* __restrict__ row, const int* __restrict__ col,
                          const float* __restrict__ ew, int* __restrict__ cursor,
                          int2* __restrict__ rec){
  int e = blockIdx.x * 256 + threadIdx.x;
  if (e < NE){
    int r = row[e];
    int p = atomicAdd(&cursor[r], 1);
    rec[p] = make_int2(col[e], __float_as_int(ew[e]));
  }
}

// ---------------- full SpMM: aggX = A @ Xb  (20000x256 bf16), R1 structure ----------------
__global__ __launch_bounds__(256) void k_spmm_full(const unsigned short* __restrict__ Xb,
    const int* __restrict__ start, const int2* __restrict__ rec,
    unsigned short* __restrict__ aggX){
  int wave = threadIdx.x >> 6, lane = threadIdx.x & 63;
  int half = lane >> 5, hl = lane & 31;
  int n = blockIdx.x * 4 + wave;          // 5000*4 = 20000 exact
  int s = start[n], e = start[n + 1];
  int d = hl * 8;                         // dims [d, d+8)
  float acc[8] = {};
  for (int base = s; base < e; base += 64){
    int p = base + lane;
    int pc = p < e ? p : e - 1;
    int2 r = rec[pc];
    float wv = (p < e) ? __int_as_float(r.y) : 0.0f;
    int m = e - base; if (m > 64) m = 64;
    for (int j = 0; j < m; j += 8){
      int j0 = j + half, j1 = j + 2 + half, j2 = j + 4 + half, j3 = j + 6 + half;
      int   c0 = __shfl(r.x, j0), c1 = __shfl(r.x, j1);
      int   c2 = __shfl(r.x, j2), c3 = __shfl(r.x, j3);
      float w0 = __shfl(wv, j0),  w1 = __shfl(wv, j1);
      float w2 = __shfl(wv, j2),  w3 = __shfl(wv, j3);
      bf16x8 v0 = *(const bf16x8*)&Xb[(size_t)c0 * 256 + d];
      bf16x8 v1 = *(const bf16x8*)&Xb[(size_t)c1 * 256 + d];
      bf16x8 v2 = *(const bf16x8*)&Xb[(size_t)c2 * 256 + d];
      bf16x8 v3 = *(const bf16x8*)&Xb[(size_t)c3 * 256 + d];
      #pragma unroll
      for (int q = 0; q < 8; ++q){
        acc[q] += w0 * bf2f((unsigned short)v0[q]) + w1 * bf2f((unsigned short)v1[q])
                + w2 * bf2f((unsigned short)v2[q]) + w3 * bf2f((unsigned short)v3[q]);
      }
    }
  }
  #pragma unroll
  for (int q = 0; q < 8; ++q){
    float o = __shfl(acc[q], hl + 32);    // lanes<32 pull odd-half partial
    acc[q] += o;
  }
  if (half == 0){
    bf16x8 ob;
    #pragma unroll
    for (int q = 0; q < 8; ++q) ob[q] = (short)f2bf(acc[q]);
    *(bf16x8*)&aggX[(size_t)n * 256 + d] = ob;
  }
}

// ---------------- staged GEMM + bias + relu: h = relu(aggX @ W1^T + b1), REP x8 ----------
__global__ __launch_bounds__(256) void k_gemm_h(const unsigned short* __restrict__ A,
                                                const unsigned short* __restrict__ Wt,
                                                const float* __restrict__ bias,
                                                unsigned short* __restrict__ out, int M){
  __shared__ unsigned short At[128 * 64];
  __shared__ unsigned short Bt[64 * 64];
  int tid = threadIdx.x, wave = tid >> 6, lane = tid & 63;
  int lm = lane & 15, lq = lane >> 4;
  int mBase = blockIdx.x * 128;
  int oBase = blockIdx.y * 64;
  for (int rep = 0; rep < 8; ++rep){
    __syncthreads();                    // protect LDS reuse across reps
    asm volatile("" ::: "memory");
    f32x4 acc[2][4] = {};
    for (int kc = 0; kc < 256; kc += 64){
      if (kc) __syncthreads();
      #pragma unroll
      for (int it = 0; it < 4; ++it){
        int s = (wave * 4 + it) * 64 + lane;
        int row = s >> 3, c = (s & 7) ^ (row & 7);
        int gr = mBase + row; if (gr >= M) gr = M - 1;
        gld_lds16(&A[(size_t)gr * 256 + kc + c * 8], &At[s * 8]);
      }
      #pragma unroll
      for (int it = 0; it < 2; ++it){
        int s = (wave * 2 + it) * 64 + lane;
        int row = s >> 3, c = (s & 7) ^ (row & 7);
        gld_lds16(&Wt[(size_t)(oBase + row) * 256 + kc + c * 8], &Bt[s * 8]);
      }
      __syncthreads();
      #pragma unroll
      for (int ks = 0; ks < 64; ks += 32){
        int cb = ks >> 3;
        int RA = wave * 32 + lm;
        int ca = ((cb + lq) ^ (RA & 7)) << 3;
        bf16x8 a0 = *(const bf16x8*)&At[RA * 64 + ca];
        bf16x8 a1 = *(const bf16x8*)&At[(RA + 16) * 64 + ca];
        #pragma unroll
        for (int os = 0; os < 4; ++os){
          int RB = os * 16 + lm;
          bf16x8 b = *(const bf16x8*)&Bt[RB * 64 + (((cb + lq) ^ (RB & 7)) << 3)];
          acc[0][os] = __builtin_amdgcn_mfma_f32_16x16x32_bf16(a0, b, acc[0][os], 0, 0, 0);
          acc[1][os] = __builtin_amdgcn_mfma_f32_16x16x32_bf16(a1, b, acc[1][os], 0, 0, 0);
        }
      }
    }
    #pragma unroll
    for (int ms = 0; ms < 2; ++ms){
      int rb = mBase + wave * 32 + ms * 16 + lq * 4;
      #pragma unroll
      for (int os = 0; os < 4; ++os){
        int col = oBase + os * 16 + lm;
        float bv = bias[col];
        #pragma unroll
        for (int r = 0; r < 4; ++r){
          int row = rb + r;
          if (row < M) out[(size_t)row * 256 + col] = f2bf(fmaxf(acc[ms][os][r] + bv, 0.f));
        }
      }
    }
  }
}

// ---------------- tail1: [0,128) sel GEMM ; [128,1152) spmm_selH — both REP x8 ----------
__global__ __launch_bounds__(256) void k_tail1(const unsigned short* __restrict__ h,
    const int* __restrict__ idx, const int* __restrict__ start, const int2* __restrict__ rec,
    unsigned short* __restrict__ aggH, const unsigned short* __restrict__ aggX,
    const unsigned short* __restrict__ Wt, const float* __restrict__ bsd,
    unsigned short* __restrict__ sel){
  int tid = threadIdx.x, wave = tid >> 6, lane = tid & 63;
  if (blockIdx.x < 128){
    int lm = lane & 15, lq = lane >> 4;
    int b2 = blockIdx.x;
    int mBase = (b2 & 31) * 128, oBase = (b2 >> 5) * 64;
    const unsigned short* W = Wt + 256 * 256;     // pre-transposed Wsd
    int r0 = mBase + wave * 32 + lm;
    for (int rep = 0; rep < 8; ++rep){
      asm volatile("" ::: "memory");
      const unsigned short* A0 = aggX + (size_t)idx[r0] * 256;
      const unsigned short* A1 = aggX + (size_t)idx[r0 + 16] * 256;
      f32x4 acc[2][4] = {};
      #pragma unroll
      for (int ks = 0; ks < 256; ks += 32){
        int ka = ks + lq * 8;
        bf16x8 a0 = *(const bf16x8*)&A0[ka];
        bf16x8 a1 = *(const bf16x8*)&A1[ka];
        #pragma unroll
        for (int os = 0; os < 4; ++os){
          bf16x8 b = *(const bf16x8*)&W[(size_t)(oBase + os * 16 + lm) * 256 + ka];
          acc[0][os] = __builtin_amdgcn_mfma_f32_16x16x32_bf16(a0, b, acc[0][os], 0, 0, 0);
          acc[1][os] = __builtin_amdgcn_mfma_f32_16x16x32_bf16(a1, b, acc[1][os], 0, 0, 0);
        }
      }
      #pragma unroll
      for (int ms = 0; ms < 2; ++ms){
        int rb = mBase + wave * 32 + ms * 16 + lq * 4;
        #pragma unroll
        for (int os = 0; os < 4; ++os){
          int col = oBase + os * 16 + lm;
          float bv = bsd[col];
          #pragma unroll
          for (int r = 0; r < 4; ++r)
            sel[(size_t)(rb + r) * 256 + col] = f2bf(acc[ms][os][r] + bv);
        }
      }
    }
    return;
  }
  // spmm_selH: aggH = A[idx] @ h
  int half = lane >> 5, hl = lane & 31;
  int i = (blockIdx.x - 128) * 4 + wave;  // 1024*4 = 4096
  int n = idx[i];
  int s = start[n], e = start[n + 1];
  int d = hl * 8;
  for (int rep = 0; rep < 8; ++rep){
    asm volatile("" ::: "memory");
    float acc[8] = {};
    for (int base = s; base < e; base += 64){
      int p = base + lane;
      int pc = p < e ? p : e - 1;
      int2 r = rec[pc];
      float wv = (p < e) ? __int_as_float(r.y) : 0.0f;
      int m = e - base; if (m > 64) m = 64;
      for (int j = 0; j < m; j += 8){
        int j0 = j + half, j1 = j + 2 + half, j2 = j + 4 + half, j3 = j + 6 + half;
        int   c0 = __shfl(r.x, j0), c1 = __shfl(r.x, j1);
        int   c2 = __shfl(r.x, j2), c3 = __shfl(r.x, j3);
        float w0 = __shfl(wv, j0),  w1 = __shfl(wv, j1);
        float w2 = __shfl(wv, j2),  w3 = __shfl(wv, j3);
        bf16x8 v0 = *(const bf16x8*)&h[(size_t)c0 * 256 + d];
        bf16x8 v1 = *(const bf16x8*)&h[(size_t)c1 * 256 + d];
        bf16x8 v2 = *(const bf16x8*)&h[(size_t)c2 * 256 + d];
        bf16x8 v3 = *(const bf16x8*)&h[(size_t)c3 * 256 + d];
        #pragma unroll
        for (int q = 0; q < 8; ++q){
          acc[q] += w0 * bf2f((unsigned short)v0[q]) + w1 * bf2f((unsigned short)v1[q])
                  + w2 * bf2f((unsigned short)v2[q]) + w3 * bf2f((unsigned short)v3[q]);
        }
      }
    }
    #pragma unroll
    for (int q = 0; q < 8; ++q){
      float o = __shfl(acc[q], hl + 32);
      acc[q] += o;
    }
    if (half == 0){
      bf16x8 ob;
      #pragma unroll
      for (int q = 0; q < 8; ++q) ob[q] = (short)f2bf(acc[q]);
      *(bf16x8*)&aggH[(size_t)i * 256 + d] = ob;
    }
  }
}

// ---------------- tail2: [0,128) out0 GEMM ; [128,656) s@s^T triangle+mirror — REP x8 ----
__global__ __launch_bounds__(256) void k_tail2(const unsigned short* __restrict__ aggH,
    const unsigned short* __restrict__ Wt, const float* __restrict__ b2v,
    float* __restrict__ out0, const unsigned short* __restrict__ S,
    float* __restrict__ out1){
  __shared__ __align__(16) char smem[34816];     // 16K At + 16K Bt, reused as 64x136 f32 stage
  int tid = threadIdx.x, wave = tid >> 6, lane = tid & 63;
  int lm = lane & 15, lq = lane >> 4;
  if (blockIdx.x < 128){
    int b2 = blockIdx.x;
    int mBase = (b2 & 31) * 128, oBase = (b2 >> 5) * 64;
    const unsigned short* W = Wt + 512 * 256;    // pre-transposed W2
    const unsigned short* A0 = aggH + (size_t)(mBase + wave * 32 + lm) * 256;
    const unsigned short* A1 = A0 + 16 * 256;
    for (int rep = 0; rep < 8; ++rep){
      asm volatile("" ::: "memory");
      f32x4 acc[2][4] = {};
      #pragma unroll
      for (int ks = 0; ks < 256; ks += 32){
        int ka = ks + lq * 8;
        bf16x8 a0 = *(const bf16x8*)&A0[ka];
        bf16x8 a1 = *(const bf16x8*)&A1[ka];
        #pragma unroll
        for (int os = 0; os < 4; ++os){
          bf16x8 b = *(const bf16x8*)&W[(size_t)(oBase + os * 16 + lm) * 256 + ka];
          acc[0][os] = __builtin_amdgcn_mfma_f32_16x16x32_bf16(a0, b, acc[0][os], 0, 0, 0);
          acc[1][os] = __builtin_amdgcn_mfma_f32_16x16x32_bf16(a1, b, acc[1][os], 0, 0, 0);
        }
      }
      #pragma unroll
      for (int ms = 0; ms < 2; ++ms){
        int rb = mBase + wave * 32 + ms * 16 + lq * 4;
        #pragma unroll
        for (int os = 0; os < 4; ++os){
          int col = oBase + os * 16 + lm;
          float bv = b2v[col];
          #pragma unroll
          for (int r = 0; r < 4; ++r)
            out0[(size_t)(rb + r) * 256 + col] = acc[ms][os][r] + bv;
        }
      }
    }
    return;
  }
  // s @ s^T, triangle block (bx, by) with by <= bx
  int t = blockIdx.x - 128;
  int bx = (int)((sqrtf(8.f * (float)t + 1.f) - 1.f) * 0.5f);
  while ((bx + 1) * (bx + 2) / 2 <= t) ++bx;
  while (bx * (bx + 1) / 2 > t) --bx;
  int by = t - bx * (bx + 1) / 2;
  int mBase = bx * 128, oBase = by * 128;
  unsigned short* At = (unsigned short*)smem;
  unsigned short* Bt = (unsigned short*)(smem + 16384);
  for (int rep = 0; rep < 8; ++rep){
    __syncthreads();                   // protect LDS reuse across reps
    asm volatile("" ::: "memory");
    f32x4 acc[2][8] = {};
    for (int kc = 0; kc < 256; kc += 64){
      if (kc) __syncthreads();
      #pragma unroll
      for (int it = 0; it < 4; ++it){
        int s = (wave * 4 + it) * 64 + lane;
        int row = s >> 3, c = (s & 7) ^ (row & 7);
        gld_lds16(&S[(size_t)(mBase + row) * 256 + kc + c * 8], &At[s * 8]);
        gld_lds16(&S[(size_t)(oBase + row) * 256 + kc + c * 8], &Bt[s * 8]);
      }
      __syncthreads();
      #pragma unroll
      for (int ks = 0; ks < 64; ks += 32){
        int cb = ks >> 3;
        int RA = wave * 32 + lm;
        int ca = ((cb + lq) ^ (RA & 7)) << 3;
        bf16x8 a0 = *(const bf16x8*)&At[RA * 64 + ca];
        bf16x8 a1 = *(const bf16x8*)&At[(RA + 16) * 64 + ca];
        #pragma unroll
        for (int os = 0; os < 8; ++os){
          int RB = os * 16 + lm;
          bf16x8 b = *(const bf16x8*)&Bt[RB * 64 + (((cb + lq) ^ (RB & 7)) << 3)];
          acc[0][os] = __builtin_amdgcn_mfma_f32_16x16x32_bf16(a0, b, acc[0][os], 0, 0, 0);
          acc[1][os] = __builtin_amdgcn_mfma_f32_16x16x32_bf16(a1, b, acc[1][os], 0, 0, 0);
        }
      }
    }
    // main tile write (rows mBase.., cols oBase..)
    #pragma unroll
    for (int ms = 0; ms < 2; ++ms){
      int rb = mBase + wave * 32 + ms * 16 + lq * 4;
      #pragma unroll
      for (int os = 0; os < 8; ++os){
        int col = oBase + os * 16 + lm;
        #pragma unroll
        for (int r = 0; r < 4; ++r)
          out1[(size_t)(rb + r) * 4096 + col] = acc[ms][os][r];
      }
    }
    if (bx != by){
      // mirror tile (rows oBase.., cols mBase..) via LDS transpose, 64 cols per pass
      float* fst = (float*)smem;                   // [oc][mr], stride 136 floats
      #pragma unroll
      for (int half = 0; half < 2; ++half){
        __syncthreads();                           // At/Bt (or prior pass) reads done
        #pragma unroll
        for (int ms = 0; ms < 2; ++ms){
          int mr = wave * 32 + ms * 16 + lq * 4;   // local row in [0,128)
          #pragma unroll
          for (int os2 = 0; os2 < 4; ++os2){
            int oc = os2 * 16 + lm;                // local col within this half, [0,64)
            *(f32x4*)&fst[oc * 136 + mr] = acc[ms][half * 4 + os2];
          }
        }
        __syncthreads();
        int l = tid & 31, ocb = tid >> 5;
        #pragma unroll
        for (int it = 0; it < 8; ++it){
          int oc = it * 8 + ocb;
          f32x4 v = *(const f32x4*)&fst[oc * 136 + l * 4];
          *(f32x4*)&out1[(size_t)(oBase + half * 64 + oc) * 4096 + mBase + l * 4] = v;
        }
      }
    }
  }
}

extern "C" void kernel_launch(void* const* d_in, const int* in_sizes, int n_in,
                              void* d_out, int out_size, void* d_ws, size_t ws_size,
                              hipStream_t stream){
  const float* X    = (const float*)d_in[0];
  const int*   erow = (const int*)d_in[1];
  const int*   ecol = (const int*)d_in[2];
  const float* ew   = (const float*)d_in[3];
  const int*   labels = (const int*)d_in[4];
  const float* W1   = (const float*)d_in[5];
  const float* b1   = (const float*)d_in[6];
  const float* W2   = (const float*)d_in[7];
  const float* b2   = (const float*)d_in[8];
  const float* Wsd  = (const float*)d_in[9];
  const float* bsd  = (const float*)d_in[10];
  float* out0 = (float*)d_out;
  float* out1 = out0 + (size_t)KSEL * 256;

  char* ws = (char*)d_ws;
  unsigned short* Xb   = (unsigned short*)(ws);               // 10,240,000
  unsigned short* Wt   = (unsigned short*)(ws + 10240000);    //    393,216
  unsigned short* aggX = (unsigned short*)(ws + 10633216);    // 10,240,000
  unsigned short* h    = (unsigned short*)(ws + 20873216);    // 10,240,000
  unsigned short* aggH = (unsigned short*)(ws + 31113216);    //  2,097,152
  unsigned short* sel  = (unsigned short*)(ws + 33210368);    //  2,097,152
  int* idx    = (int*)(ws + 35307520);                        //     16,384
  int* counts = (int*)(ws + 35323904);                        //     80,000
  int* startp = (int*)(ws + 35403904);                        //     80,004
  int* cursor = (int*)(ws + 35483908);                        //     80,000
  int2* rec   = (int2*)(ws + 35563912);                       //  2,560,000
  int* partA  = (int*)(ws + 38123912);                        //        128

  k_prep0<<<68, 256, 0, stream>>>(W1, Wsd, W2, labels, Wt, counts, partA);
  k_main1<<<3770, 256, 0, stream>>>(X, erow, labels, partA, Xb, counts, idx);
  k_row_emit<<<20, 256, 0, stream>>>(counts, startp, cursor);
  k_scatter<<<1250, 256, 0, stream>>>(erow, ecol, ew, cursor, rec);
  k_spmm_full<<<5000, 256, 0, stream>>>(Xb, startp, rec, aggX);
  k_gemm_h<<<dim3(157, 4), 256, 0, stream>>>(aggX, Wt, b1, h, NN);
  k_tail1<<<1152, 256, 0, stream>>>(h, idx, startp, rec, aggH, aggX, Wt, bsd, sel);
  k_tail2<<<656, 256, 0, stream>>>(aggH, Wt, b2, out0, sel, out1);
}

// Round 8
// 202.131 us; speedup vs baseline: 2.3280x; 2.3280x over previous
//
#include <hip/hip_runtime.h>
#include <hip/hip_bf16.h>

#define NN   20000
#define NE   320000
#define KSEL 4096

typedef short bf16x8 __attribute__((ext_vector_type(8)));
typedef float f32x4  __attribute__((ext_vector_type(4)));

static __device__ __forceinline__ float bf2f(unsigned short u){
  return __uint_as_float(((unsigned int)u) << 16);
}
static __device__ __forceinline__ unsigned short f2bf(float f){
  unsigned int x = __float_as_uint(f);
  x += 0x7fffu + ((x >> 16) & 1u);   // round-to-nearest-even
  return (unsigned short)(x >> 16);
}
// async global->LDS, 16B/lane; LDS dest = wave-uniform base + lane*16
static __device__ __forceinline__ void gld_lds16(const unsigned short* g, unsigned short* l){
  __builtin_amdgcn_global_load_lds(
      (const __attribute__((address_space(1))) unsigned int*)g,
      (__attribute__((address_space(3))) unsigned int*)l, 16, 0, 0);
}

// ---------------- prep0: [0,48) W 64x64 tile-transpose ; [48,68) zero counts + label partials
__global__ __launch_bounds__(256) void k_prep0(const float* __restrict__ W1,
    const float* __restrict__ Wsd, const float* __restrict__ W2,
    const int* __restrict__ labels,
    unsigned short* __restrict__ Wt, int* __restrict__ counts, int* __restrict__ partA){
  int b = blockIdx.x, tid = threadIdx.x;
  if (b < 48){
    __shared__ unsigned short lt[64 * 65];
    int w = b >> 4, t = b & 15;
    int tR = (t >> 2) * 64, tC = (t & 3) * 64;    // k-block, o-block
    const float* W = (w == 0) ? W1 : (w == 1 ? Wsd : W2);
    #pragma unroll
    for (int it = 0; it < 16; ++it){
      int lin = it * 256 + tid;
      int r = lin >> 6, c = lin & 63;             // k-off, o-off (coalesced read)
      lt[c * 65 + r] = f2bf(W[(size_t)(tR + r) * 256 + tC + c]);
    }
    __syncthreads();
    #pragma unroll
    for (int it = 0; it < 16; ++it){
      int lin = it * 256 + tid;
      int o = lin >> 6, k = lin & 63;             // coalesced write
      Wt[(size_t)w * 65536 + (size_t)(tC + o) * 256 + tR + k] = lt[o * 65 + k];
    }
  } else {
    __shared__ int ws[4];
    int z = b - 48, lane = tid & 63, wv = tid >> 6;
    if (tid < 250) *(int4*)&counts[z * 1000 + tid * 4] = make_int4(0, 0, 0, 0);
    int base = z * 1024 + tid * 4;
    int s = 0;
    #pragma unroll
    for (int j = 0; j < 4; ++j){
      int n0 = base + j;
      if (n0 < NN) s += (labels[n0] == 1) ? 1 : 0;
    }
    #pragma unroll
    for (int off = 32; off; off >>= 1) s += __shfl_down(s, off, 64);
    if (lane == 0) ws[wv] = s;
    __syncthreads();
    if (tid == 0) partA[z] = ws[0] + ws[1] + ws[2] + ws[3];
  }
}

// ---------------- main1: [0,2500) X->bf16 ; [2500,3750) histogram ; [3750,3770) idx emit
__global__ __launch_bounds__(256) void k_main1(const float* __restrict__ X,
    const int* __restrict__ row, const int* __restrict__ labels,
    const int* __restrict__ partA,
    unsigned short* __restrict__ Xb, int* __restrict__ counts, int* __restrict__ idx){
  int b = blockIdx.x, tid = threadIdx.x;
  if (b < 2500){
    int i = (b * 256 + tid) * 8;
    float4 v0 = *(const float4*)(X + i);
    float4 v1 = *(const float4*)(X + i + 4);
    bf16x8 o;
    o[0] = (short)f2bf(v0.x); o[1] = (short)f2bf(v0.y);
    o[2] = (short)f2bf(v0.z); o[3] = (short)f2bf(v0.w);
    o[4] = (short)f2bf(v1.x); o[5] = (short)f2bf(v1.y);
    o[6] = (short)f2bf(v1.z); o[7] = (short)f2bf(v1.w);
    *(bf16x8*)(Xb + i) = o;
  } else if (b < 3750){
    int e = (b - 2500) * 256 + tid;
    atomicAdd(&counts[row[e]], 1);
  } else {
    __shared__ int ws[4];
    __shared__ int boff_s;
    int bx = b - 3750;
    int lane = tid & 63, wv = tid >> 6;
    if (tid < 64){
      int v = (lane < 20) ? partA[lane] : 0;
      int acc = v;
      #pragma unroll
      for (int off = 1; off < 32; off <<= 1){
        int t = __shfl_up(acc, off, 64);
        if (lane >= off) acc += t;
      }
      if (lane == bx) boff_s = acc - v;   // exclusive prefix
    }
    int base = bx * 1024 + tid * 4;
    int c[4]; int s = 0;
    #pragma unroll
    for (int j = 0; j < 4; ++j){
      int n0 = base + j;
      c[j] = (n0 < NN && labels[n0] == 1) ? 1 : 0;
      s += c[j];
    }
    int incl = s;
    #pragma unroll
    for (int off = 1; off < 64; off <<= 1){
      int t = __shfl_up(incl, off, 64);
      if (lane >= off) incl += t;
    }
    if (lane == 63) ws[wv] = incl;
    __syncthreads();
    int woff = boff_s;
    for (int w = 0; w < wv; ++w) woff += ws[w];
    int off = woff + incl - s;
    #pragma unroll
    for (int j = 0; j < 4; ++j){
      if (c[j]){ if (off < KSEL) idx[off] = base + j; ++off; }
    }
  }
}

// 20 blocks; each sums counts[0..base) itself, then scans its 1024-window -> start/cursor
__global__ __launch_bounds__(256) void k_row_emit(const int* __restrict__ counts,
    int* __restrict__ start, int* __restrict__ cursor){
  __shared__ int ws[4];
  __shared__ int red[4];
  int tid = threadIdx.x, lane = tid & 63, wv = tid >> 6;
  int base = blockIdx.x * 1024;
  int ps = 0;
  for (int i = tid * 4; i < base; i += 1024){
    int4 v = *(const int4*)&counts[i];
    ps += v.x + v.y + v.z + v.w;
  }
  #pragma unroll
  for (int off = 32; off; off >>= 1) ps += __shfl_down(ps, off, 64);
  if (lane == 0) red[wv] = ps;
  __syncthreads();
  int bpref = red[0] + red[1] + red[2] + red[3];
  int nb = base + tid * 4;
  int c[4]; int s = 0;
  #pragma unroll
  for (int j = 0; j < 4; ++j){
    int n0 = nb + j;
    c[j] = (n0 < NN) ? counts[n0] : 0;
    s += c[j];
  }
  int incl = s;
  #pragma unroll
  for (int off = 1; off < 64; off <<= 1){
    int t = __shfl_up(incl, off, 64);
    if (lane >= off) incl += t;
  }
  if (lane == 63) ws[wv] = incl;
  __syncthreads();
  int woff = bpref;
  for (int w = 0; w < wv; ++w) woff += ws[w];
  int run = woff + incl - s;
  #pragma unroll
  for (int j = 0; j < 4; ++j){
    int n0 = nb + j;
    if (n0 < NN){ start[n0] = run; cursor[n0] = run; run += c[j]; }
  }
  if (blockIdx.x == 0 && tid == 0) start[NN] = NE;
}

__global__ void k_scatter(const int* __restrict__ row, const int* __restrict__ col,
                          const float* __restrict__ ew, int* __restrict__ cursor,
                          int2* __restrict__ rec){
  int e = blockIdx.x * 256 + threadIdx.x;
  if (e < NE){
    int r = row[e];
    int p = atomicAdd(&cursor[r], 1);
    rec[p] = make_int2(col[e], __float_as_int(ew[e]));
  }
}

// ---------------- full SpMM: aggX = A @ Xb  (20000x256 bf16), R1 structure ----------------
__global__ __launch_bounds__(256) void k_spmm_full(const unsigned short* __restrict__ Xb,
    const int* __restrict__ start, const int2* __restrict__ rec,
    unsigned short* __restrict__ aggX){
  int wave = threadIdx.x >> 6, lane = threadIdx.x & 63;
  int half = lane >> 5, hl = lane & 31;
  int n = blockIdx.x * 4 + wave;          // 5000*4 = 20000 exact
  int s = start[n], e = start[n + 1];
  int d = hl * 8;                         // dims [d, d+8)
  float acc[8] = {};
  for (int base = s; base < e; base += 64){
    int p = base + lane;
    int pc = p < e ? p : e - 1;
    int2 r = rec[pc];
    float wv = (p < e) ? __int_as_float(r.y) : 0.0f;
    int m = e - base; if (m > 64) m = 64;
    for (int j = 0; j < m; j += 8){
      int j0 = j + half, j1 = j + 2 + half, j2 = j + 4 + half, j3 = j + 6 + half;
      int   c0 = __shfl(r.x, j0), c1 = __shfl(r.x, j1);
      int   c2 = __shfl(r.x, j2), c3 = __shfl(r.x, j3);
      float w0 = __shfl(wv, j0),  w1 = __shfl(wv, j1);
      float w2 = __shfl(wv, j2),  w3 = __shfl(wv, j3);
      bf16x8 v0 = *(const bf16x8*)&Xb[(size_t)c0 * 256 + d];
      bf16x8 v1 = *(const bf16x8*)&Xb[(size_t)c1 * 256 + d];
      bf16x8 v2 = *(const bf16x8*)&Xb[(size_t)c2 * 256 + d];
      bf16x8 v3 = *(const bf16x8*)&Xb[(size_t)c3 * 256 + d];
      #pragma unroll
      for (int q = 0; q < 8; ++q){
        acc[q] += w0 * bf2f((unsigned short)v0[q]) + w1 * bf2f((unsigned short)v1[q])
                + w2 * bf2f((unsigned short)v2[q]) + w3 * bf2f((unsigned short)v3[q]);
      }
    }
  }
  #pragma unroll
  for (int q = 0; q < 8; ++q){
    float o = __shfl(acc[q], hl + 32);    // lanes<32 pull odd-half partial
    acc[q] += o;
  }
  if (half == 0){
    bf16x8 ob;
    #pragma unroll
    for (int q = 0; q < 8; ++q) ob[q] = (short)f2bf(acc[q]);
    *(bf16x8*)&aggX[(size_t)n * 256 + d] = ob;
  }
}

// ---------------- staged GEMM + bias + relu: h = relu(aggX @ W1^T + b1) ----------------
__global__ __launch_bounds__(256) void k_gemm_h(const unsigned short* __restrict__ A,
                                                const unsigned short* __restrict__ Wt,
                                                const float* __restrict__ bias,
                                                unsigned short* __restrict__ out, int M){
  __shared__ unsigned short At[128 * 64];
  __shared__ unsigned short Bt[64 * 64];
  int tid = threadIdx.x, wave = tid >> 6, lane = tid & 63;
  int lm = lane & 15, lq = lane >> 4;
  int mBase = blockIdx.x * 128;
  int oBase = blockIdx.y * 64;
  f32x4 acc[2][4] = {};
  for (int kc = 0; kc < 256; kc += 64){
    if (kc) __syncthreads();
    #pragma unroll
    for (int it = 0; it < 4; ++it){
      int s = (wave * 4 + it) * 64 + lane;
      int row = s >> 3, c = (s & 7) ^ (row & 7);
      int gr = mBase + row; if (gr >= M) gr = M - 1;
      gld_lds16(&A[(size_t)gr * 256 + kc + c * 8], &At[s * 8]);
    }
    #pragma unroll
    for (int it = 0; it < 2; ++it){
      int s = (wave * 2 + it) * 64 + lane;
      int row = s >> 3, c = (s & 7) ^ (row & 7);
      gld_lds16(&Wt[(size_t)(oBase + row) * 256 + kc + c * 8], &Bt[s * 8]);
    }
    __syncthreads();
    #pragma unroll
    for (int ks = 0; ks < 64; ks += 32){
      int cb = ks >> 3;
      int RA = wave * 32 + lm;
      int ca = ((cb + lq) ^ (RA & 7)) << 3;
      bf16x8 a0 = *(const bf16x8*)&At[RA * 64 + ca];
      bf16x8 a1 = *(const bf16x8*)&At[(RA + 16) * 64 + ca];
      #pragma unroll
      for (int os = 0; os < 4; ++os){
        int RB = os * 16 + lm;
        bf16x8 b = *(const bf16x8*)&Bt[RB * 64 + (((cb + lq) ^ (RB & 7)) << 3)];
        acc[0][os] = __builtin_amdgcn_mfma_f32_16x16x32_bf16(a0, b, acc[0][os], 0, 0, 0);
        acc[1][os] = __builtin_amdgcn_mfma_f32_16x16x32_bf16(a1, b, acc[1][os], 0, 0, 0);
      }
    }
  }
  #pragma unroll
  for (int ms = 0; ms < 2; ++ms){
    int rb = mBase + wave * 32 + ms * 16 + lq * 4;
    #pragma unroll
    for (int os = 0; os < 4; ++os){
      int col = oBase + os * 16 + lm;
      float bv = bias[col];
      #pragma unroll
      for (int r = 0; r < 4; ++r){
        int row = rb + r;
        if (row < M) out[(size_t)row * 256 + col] = f2bf(fmaxf(acc[ms][os][r] + bv, 0.f));
      }
    }
  }
}

// ---------------- tail1: [0,128) sel = aggX[idx]@Wsd+bsd (bf16) ; [128,1152) spmm_selH ----
__global__ __launch_bounds__(256) void k_tail1(const unsigned short* __restrict__ h,
    const int* __restrict__ idx, const int* __restrict__ start, const int2* __restrict__ rec,
    unsigned short* __restrict__ aggH, const unsigned short* __restrict__ aggX,
    const unsigned short* __restrict__ Wt, const float* __restrict__ bsd,
    unsigned short* __restrict__ sel){
  int tid = threadIdx.x, wave = tid >> 6, lane = tid & 63;
  if (blockIdx.x < 128){
    // z1 GEMM, B rows read straight from L2 (Wsd tile = 128 KB, hot)
    int lm = lane & 15, lq = lane >> 4;
    int b2 = blockIdx.x;
    int mBase = (b2 & 31) * 128, oBase = (b2 >> 5) * 64;
    const unsigned short* W = Wt + 256 * 256;     // pre-transposed Wsd
    int r0 = mBase + wave * 32 + lm;
    const unsigned short* A0 = aggX + (size_t)idx[r0] * 256;
    const unsigned short* A1 = aggX + (size_t)idx[r0 + 16] * 256;
    f32x4 acc[2][4] = {};
    #pragma unroll
    for (int ks = 0; ks < 256; ks += 32){
      int ka = ks + lq * 8;
      bf16x8 a0 = *(const bf16x8*)&A0[ka];
      bf16x8 a1 = *(const bf16x8*)&A1[ka];
      #pragma unroll
      for (int os = 0; os < 4; ++os){
        bf16x8 b = *(const bf16x8*)&W[(size_t)(oBase + os * 16 + lm) * 256 + ka];
        acc[0][os] = __builtin_amdgcn_mfma_f32_16x16x32_bf16(a0, b, acc[0][os], 0, 0, 0);
        acc[1][os] = __builtin_amdgcn_mfma_f32_16x16x32_bf16(a1, b, acc[1][os], 0, 0, 0);
      }
    }
    #pragma unroll
    for (int ms = 0; ms < 2; ++ms){
      int rb = mBase + wave * 32 + ms * 16 + lq * 4;
      #pragma unroll
      for (int os = 0; os < 4; ++os){
        int col = oBase + os * 16 + lm;
        float bv = bsd[col];
        #pragma unroll
        for (int r = 0; r < 4; ++r)
          sel[(size_t)(rb + r) * 256 + col] = f2bf(acc[ms][os][r] + bv);
      }
    }
    return;
  }
  // spmm_selH: aggH = A[idx] @ h
  int half = lane >> 5, hl = lane & 31;
  int i = (blockIdx.x - 128) * 4 + wave;  // 1024*4 = 4096
  int n = idx[i];
  int s = start[n], e = start[n + 1];
  int d = hl * 8;
  float acc[8] = {};
  for (int base = s; base < e; base += 64){
    int p = base + lane;
    int pc = p < e ? p : e - 1;
    int2 r = rec[pc];
    float wv = (p < e) ? __int_as_float(r.y) : 0.0f;
    int m = e - base; if (m > 64) m = 64;
    for (int j = 0; j < m; j += 8){
      int j0 = j + half, j1 = j + 2 + half, j2 = j + 4 + half, j3 = j + 6 + half;
      int   c0 = __shfl(r.x, j0), c1 = __shfl(r.x, j1);
      int   c2 = __shfl(r.x, j2), c3 = __shfl(r.x, j3);
      float w0 = __shfl(wv, j0),  w1 = __shfl(wv, j1);
      float w2 = __shfl(wv, j2),  w3 = __shfl(wv, j3);
      bf16x8 v0 = *(const bf16x8*)&h[(size_t)c0 * 256 + d];
      bf16x8 v1 = *(const bf16x8*)&h[(size_t)c1 * 256 + d];
      bf16x8 v2 = *(const bf16x8*)&h[(size_t)c2 * 256 + d];
      bf16x8 v3 = *(const bf16x8*)&h[(size_t)c3 * 256 + d];
      #pragma unroll
      for (int q = 0; q < 8; ++q){
        acc[q] += w0 * bf2f((unsigned short)v0[q]) + w1 * bf2f((unsigned short)v1[q])
                + w2 * bf2f((unsigned short)v2[q]) + w3 * bf2f((unsigned short)v3[q]);
      }
    }
  }
  #pragma unroll
  for (int q = 0; q < 8; ++q){
    float o = __shfl(acc[q], hl + 32);
    acc[q] += o;
  }
  if (half == 0){
    bf16x8 ob;
    #pragma unroll
    for (int q = 0; q < 8; ++q) ob[q] = (short)f2bf(acc[q]);
    *(bf16x8*)&aggH[(size_t)i * 256 + d] = ob;
  }
}

// ---------------- tail2: [0,128) out0 = aggH@W2+b2 (f32) ; [128,656) s@s^T upper triangle.
// Main-tile epilogue restaged through LDS -> 256B-contiguous write segments (was 64B
// partial-line segments; theory: half-line writes cost ~2x HBM write BW). Mirror unchanged.
__global__ __launch_bounds__(256) void k_tail2(const unsigned short* __restrict__ aggH,
    const unsigned short* __restrict__ Wt, const float* __restrict__ b2v,
    float* __restrict__ out0, const unsigned short* __restrict__ S,
    float* __restrict__ out1){
  __shared__ __align__(16) char smem[34816];     // 16K At + 16K Bt; reused as f32 stage
  int tid = threadIdx.x, wave = tid >> 6, lane = tid & 63;
  int lm = lane & 15, lq = lane >> 4;
  if (blockIdx.x < 128){
    // z0 GEMM, B straight from L2 (W2 tile hot)
    int b2 = blockIdx.x;
    int mBase = (b2 & 31) * 128, oBase = (b2 >> 5) * 64;
    const unsigned short* W = Wt + 512 * 256;    // pre-transposed W2
    const unsigned short* A0 = aggH + (size_t)(mBase + wave * 32 + lm) * 256;
    const unsigned short* A1 = A0 + 16 * 256;
    f32x4 acc[2][4] = {};
    #pragma unroll
    for (int ks = 0; ks < 256; ks += 32){
      int ka = ks + lq * 8;
      bf16x8 a0 = *(const bf16x8*)&A0[ka];
      bf16x8 a1 = *(const bf16x8*)&A1[ka];
      #pragma unroll
      for (int os = 0; os < 4; ++os){
        bf16x8 b = *(const bf16x8*)&W[(size_t)(oBase + os * 16 + lm) * 256 + ka];
        acc[0][os] = __builtin_amdgcn_mfma_f32_16x16x32_bf16(a0, b, acc[0][os], 0, 0, 0);
        acc[1][os] = __builtin_amdgcn_mfma_f32_16x16x32_bf16(a1, b, acc[1][os], 0, 0, 0);
      }
    }
    #pragma unroll
    for (int ms = 0; ms < 2; ++ms){
      int rb = mBase + wave * 32 + ms * 16 + lq * 4;
      #pragma unroll
      for (int os = 0; os < 4; ++os){
        int col = oBase + os * 16 + lm;
        float bv = b2v[col];
        #pragma unroll
        for (int r = 0; r < 4; ++r)
          out0[(size_t)(rb + r) * 256 + col] = acc[ms][os][r] + bv;
      }
    }
    return;
  }
  // s @ s^T, triangle block (bx, by) with by <= bx
  int t = blockIdx.x - 128;
  int bx = (int)((sqrtf(8.f * (float)t + 1.f) - 1.f) * 0.5f);
  while ((bx + 1) * (bx + 2) / 2 <= t) ++bx;
  while (bx * (bx + 1) / 2 > t) --bx;
  int by = t - bx * (bx + 1) / 2;
  int mBase = bx * 128, oBase = by * 128;
  unsigned short* At = (unsigned short*)smem;
  unsigned short* Bt = (unsigned short*)(smem + 16384);
  f32x4 acc[2][8] = {};
  for (int kc = 0; kc < 256; kc += 64){
    if (kc) __syncthreads();
    #pragma unroll
    for (int it = 0; it < 4; ++it){
      int s = (wave * 4 + it) * 64 + lane;
      int row = s >> 3, c = (s & 7) ^ (row & 7);
      gld_lds16(&S[(size_t)(mBase + row) * 256 + kc + c * 8], &At[s * 8]);
      gld_lds16(&S[(size_t)(oBase + row) * 256 + kc + c * 8], &Bt[s * 8]);
    }
    __syncthreads();
    #pragma unroll
    for (int ks = 0; ks < 64; ks += 32){
      int cb = ks >> 3;
      int RA = wave * 32 + lm;
      int ca = ((cb + lq) ^ (RA & 7)) << 3;
      bf16x8 a0 = *(const bf16x8*)&At[RA * 64 + ca];
      bf16x8 a1 = *(const bf16x8*)&At[(RA + 16) * 64 + ca];
      #pragma unroll
      for (int os = 0; os < 8; ++os){
        int RB = os * 16 + lm;
        bf16x8 b = *(const bf16x8*)&Bt[RB * 64 + (((cb + lq) ^ (RB & 7)) << 3)];
        acc[0][os] = __builtin_amdgcn_mfma_f32_16x16x32_bf16(a0, b, acc[0][os], 0, 0, 0);
        acc[1][os] = __builtin_amdgcn_mfma_f32_16x16x32_bf16(a1, b, acc[1][os], 0, 0, 0);
      }
    }
  }
  // main tile write via LDS restage [row][68] -> f32x4 lanes, 256B row segments
  float* fst = (float*)smem;                     // 128 x 68 floats = 34816 B exactly
  #pragma unroll
  for (int half = 0; half < 2; ++half){
    __syncthreads();                             // At/Bt reads (or prior pass reads) done
    #pragma unroll
    for (int ms = 0; ms < 2; ++ms){
      int mr = wave * 32 + ms * 16 + lq * 4;     // local row base
      #pragma unroll
      for (int os2 = 0; os2 < 4; ++os2){
        int oc = os2 * 16 + lm;                  // local col within this half, [0,64)
        #pragma unroll
        for (int r = 0; r < 4; ++r)
          fst[(mr + r) * 68 + oc] = acc[ms][half * 4 + os2][r];
      }
    }
    __syncthreads();
    int cc = (tid & 15) * 4, r0 = tid >> 4;
    #pragma unroll
    for (int it = 0; it < 8; ++it){
      int row = it * 16 + r0;
      f32x4 v = *(const f32x4*)&fst[row * 68 + cc];
      *(f32x4*)&out1[(size_t)(mBase + row) * 4096 + oBase + half * 64 + cc] = v;
    }
  }
  if (bx == by) return;
  // mirror tile (rows oBase.., cols mBase..) via LDS transpose, 64 cols per pass
  #pragma unroll
  for (int half = 0; half < 2; ++half){
    __syncthreads();                             // prior pass reads done
    #pragma unroll
    for (int ms = 0; ms < 2; ++ms){
      int mr = wave * 32 + ms * 16 + lq * 4;     // local row in [0,128)
      #pragma unroll
      for (int os2 = 0; os2 < 4; ++os2){
        int oc = os2 * 16 + lm;                  // local col within this half, [0,64)
        *(f32x4*)&fst[oc * 136 + mr] = acc[ms][half * 4 + os2];
      }
    }
    __syncthreads();
    int l = tid & 31, ocb = tid >> 5;
    #pragma unroll
    for (int it = 0; it < 8; ++it){
      int oc = it * 8 + ocb;
      f32x4 v = *(const f32x4*)&fst[oc * 136 + l * 4];
      *(f32x4*)&out1[(size_t)(oBase + half * 64 + oc) * 4096 + mBase + l * 4] = v;
    }
  }
}

extern "C" void kernel_launch(void* const* d_in, const int* in_sizes, int n_in,
                              void* d_out, int out_size, void* d_ws, size_t ws_size,
                              hipStream_t stream){
  const float* X    = (const float*)d_in[0];
  const int*   erow = (const int*)d_in[1];
  const int*   ecol = (const int*)d_in[2];
  const float* ew   = (const float*)d_in[3];
  const int*   labels = (const int*)d_in[4];
  const float* W1   = (const float*)d_in[5];
  const float* b1   = (const float*)d_in[6];
  const float* W2   = (const float*)d_in[7];
  const float* b2   = (const float*)d_in[8];
  const float* Wsd  = (const float*)d_in[9];
  const float* bsd  = (const float*)d_in[10];
  float* out0 = (float*)d_out;
  float* out1 = out0 + (size_t)KSEL * 256;

  char* ws = (char*)d_ws;
  unsigned short* Xb   = (unsigned short*)(ws);               // 10,240,000
  unsigned short* Wt   = (unsigned short*)(ws + 10240000);    //    393,216
  unsigned short* aggX = (unsigned short*)(ws + 10633216);    // 10,240,000
  unsigned short* h    = (unsigned short*)(ws + 20873216);    // 10,240,000
  unsigned short* aggH = (unsigned short*)(ws + 31113216);    //  2,097,152
  unsigned short* sel  = (unsigned short*)(ws + 33210368);    //  2,097,152
  int* idx    = (int*)(ws + 35307520);                        //     16,384
  int* counts = (int*)(ws + 35323904);                        //     80,000
  int* startp = (int*)(ws + 35403904);                        //     80,004
  int* cursor = (int*)(ws + 35483908);                        //     80,000
  int2* rec   = (int2*)(ws + 35563912);                       //  2,560,000
  int* partA  = (int*)(ws + 38123912);                        //        128

  k_prep0<<<68, 256, 0, stream>>>(W1, Wsd, W2, labels, Wt, counts, partA);
  k_main1<<<3770, 256, 0, stream>>>(X, erow, labels, partA, Xb, counts, idx);
  k_row_emit<<<20, 256, 0, stream>>>(counts, startp, cursor);
  k_scatter<<<1250, 256, 0, stream>>>(erow, ecol, ew, cursor, rec);
  k_spmm_full<<<5000, 256, 0, stream>>>(Xb, startp, rec, aggX);
  k_gemm_h<<<dim3(157, 4), 256, 0, stream>>>(aggX, Wt, b1, h, NN);
  k_tail1<<<1152, 256, 0, stream>>>(h, idx, startp, rec, aggH, aggX, Wt, bsd, sel);
  k_tail2<<<656, 256, 0, stream>>>(aggH, Wt, b2, out0, sel, out1);
}